// Round 1
// baseline (100.390 us; speedup 1.0000x reference)
//
#include <hip/hip_runtime.h>

#define HID 64
#define NROWS 1036
#define KNOTS 64   // intervals; table has KNOTS+1 rows

// Static device-global table: g(p_j) for p_j = j/KNOTS, j = 0..KNOTS.
// Rebuilt every kernel_launch (deterministic), no d_ws dependence.
__device__ __align__(16) float gTable[(KNOTS + 1) * NROWS];

__global__ void build_table_kernel(const float* __restrict__ Wh1,
                                   const float* __restrict__ Bh1,
                                   const float* __restrict__ Wh2,
                                   const float* __restrict__ Bh2) {
    __shared__ float h[HID];
    const int j = blockIdx.x;                      // 0..KNOTS
    const float p = (float)j / (float)KNOTS;
    const int t = threadIdx.x;
    if (t < HID) h[t] = tanhf(fmaf(p, Wh1[t], Bh1[t]));
    __syncthreads();
    for (int i = t; i < NROWS; i += blockDim.x) {
        const float* row = Wh2 + i * HID;
        float acc = Bh2[i];
        #pragma unroll
        for (int k = 0; k < HID; ++k) acc = fmaf(row[k], h[k], acc);
        gTable[j * NROWS + i] = acc;
    }
}

__device__ inline float wave_sum(float v) {
    #pragma unroll
    for (int m = 32; m >= 1; m >>= 1) v += __shfl_xor(v, m, 64);
    return v;
}

__device__ inline float lerp1(float lo, float hi, float f) {
    return fmaf(f, hi - lo, lo);
}

__global__ __launch_bounds__(256) void hyper_main(
    const float* __restrict__ coords, const float* __restrict__ param,
    const float* __restrict__ W1, const float* __restrict__ B1,
    const float* __restrict__ W2, const float* __restrict__ B2,
    const float* __restrict__ W3, const float* __restrict__ B3,
    float* __restrict__ out, int n) {
    __shared__ float w2t[HID * HID];   // W2 transposed: w2t[k*64 + h] = W2[h][k]
    __shared__ float x1s[4][HID];

    const int tid = threadIdx.x;

    // Stage W2 transposed into LDS (one-time per block).
    for (int idx = tid; idx < HID * HID; idx += 256) {
        const int hh = idx >> 6, kk = idx & 63;
        w2t[kk * HID + hh] = W2[idx];
    }

    const int wid = tid >> 6;          // wave id 0..3
    const int lane = tid & 63;         // = hidden index
    int s = blockIdx.x * 4 + wid;      // sample
    const bool valid = (s < n);
    if (s >= n) s = n - 1;

    const float c0 = coords[2 * s];
    const float c1 = coords[2 * s + 1];
    const float p = param[s];

    float pf = p * (float)KNOTS;
    int j = (int)pf;
    j = max(0, min(KNOTS - 1, j));
    const float f = pf - (float)j;

    const float* T0 = gTable + j * NROWS;
    const float* T1 = T0 + NROWS;

    // ---- per-lane low-rank fragments (lerped) ----
    float b1v[4], b2v[4], a2v[4], a3v[4], a1v[8], b3v[4];
    {
        const float4 lo = *(const float4*)(T0 + 8 + 4 * lane);
        const float4 hi = *(const float4*)(T1 + 8 + 4 * lane);
        b1v[0] = lerp1(lo.x, hi.x, f); b1v[1] = lerp1(lo.y, hi.y, f);
        b1v[2] = lerp1(lo.z, hi.z, f); b1v[3] = lerp1(lo.w, hi.w, f);
    }
    {
        const float4 lo = *(const float4*)(T0 + 520 + 4 * lane);
        const float4 hi = *(const float4*)(T1 + 520 + 4 * lane);
        b2v[0] = lerp1(lo.x, hi.x, f); b2v[1] = lerp1(lo.y, hi.y, f);
        b2v[2] = lerp1(lo.z, hi.z, f); b2v[3] = lerp1(lo.w, hi.w, f);
    }
    #pragma unroll
    for (int r = 0; r < 4; ++r) {
        a2v[r] = lerp1(T0[264 + 64 * r + lane], T1[264 + 64 * r + lane], f);
        a3v[r] = lerp1(T0[776 + 64 * r + lane], T1[776 + 64 * r + lane], f);
    }
    {   // shared across lanes: a1 rows 0..7, b3 rows 1032..1035
        const float4 lo0 = *(const float4*)(T0 + 0);
        const float4 hi0 = *(const float4*)(T1 + 0);
        const float4 lo1 = *(const float4*)(T0 + 4);
        const float4 hi1 = *(const float4*)(T1 + 4);
        a1v[0] = lerp1(lo0.x, hi0.x, f); a1v[1] = lerp1(lo0.y, hi0.y, f);
        a1v[2] = lerp1(lo0.z, hi0.z, f); a1v[3] = lerp1(lo0.w, hi0.w, f);
        a1v[4] = lerp1(lo1.x, hi1.x, f); a1v[5] = lerp1(lo1.y, hi1.y, f);
        a1v[6] = lerp1(lo1.z, hi1.z, f); a1v[7] = lerp1(lo1.w, hi1.w, f);
        const float4 lo2 = *(const float4*)(T0 + 1032);
        const float4 hi2 = *(const float4*)(T1 + 1032);
        b3v[0] = lerp1(lo2.x, hi2.x, f); b3v[1] = lerp1(lo2.y, hi2.y, f);
        b3v[2] = lerp1(lo2.z, hi2.z, f); b3v[3] = lerp1(lo2.w, hi2.w, f);
    }

    // ---- layer 1 ----
    float t1r[4];
    #pragma unroll
    for (int r = 0; r < 4; ++r)
        t1r[r] = fmaf(c0, a1v[2 * r], c1 * a1v[2 * r + 1]);
    float lr1 = t1r[0] * b1v[0] + t1r[1] * b1v[1] + t1r[2] * b1v[2] + t1r[3] * b1v[3];
    const float pre1 = fmaf(c0, W1[2 * lane], fmaf(c1, W1[2 * lane + 1], lr1 + B1[lane]));
    const float x1 = tanhf(pre1);

    x1s[wid][lane] = x1;
    __syncthreads();   // covers both w2t staging and x1s

    // ---- W2 @ x1 (per-lane row dot) ----
    float ac0 = 0.f, ac1 = 0.f, ac2 = 0.f, ac3 = 0.f;
    #pragma unroll
    for (int k = 0; k < HID; k += 4) {
        ac0 = fmaf(w2t[(k + 0) * HID + lane], x1s[wid][k + 0], ac0);
        ac1 = fmaf(w2t[(k + 1) * HID + lane], x1s[wid][k + 1], ac1);
        ac2 = fmaf(w2t[(k + 2) * HID + lane], x1s[wid][k + 2], ac2);
        ac3 = fmaf(w2t[(k + 3) * HID + lane], x1s[wid][k + 3], ac3);
    }
    const float w2row = (ac0 + ac1) + (ac2 + ac3);

    // ---- low-rank 2: t2[r] = sum_k x1[k]*a2[r][k] (cross-lane) ----
    float t2r[4];
    #pragma unroll
    for (int r = 0; r < 4; ++r) t2r[r] = wave_sum(x1 * a2v[r]);
    const float lr2 = t2r[0] * b2v[0] + t2r[1] * b2v[1] + t2r[2] * b2v[2] + t2r[3] * b2v[3];
    const float x2 = tanhf(w2row + lr2 + B2[lane]);

    // ---- output layer ----
    float o = wave_sum(W3[lane] * x2);
    float t3r[4];
    #pragma unroll
    for (int r = 0; r < 4; ++r) t3r[r] = wave_sum(x2 * a3v[r]);

    if (lane == 0 && valid) {
        out[s] = o + t3r[0] * b3v[0] + t3r[1] * b3v[1] + t3r[2] * b3v[2]
                   + t3r[3] * b3v[3] + B3[0];
    }
}

extern "C" void kernel_launch(void* const* d_in, const int* in_sizes, int n_in,
                              void* d_out, int out_size, void* d_ws, size_t ws_size,
                              hipStream_t stream) {
    const float* coords = (const float*)d_in[0];
    const float* param  = (const float*)d_in[1];
    const float* W1  = (const float*)d_in[2];
    const float* B1  = (const float*)d_in[3];
    const float* W2  = (const float*)d_in[4];
    const float* B2  = (const float*)d_in[5];
    const float* W3  = (const float*)d_in[6];
    const float* B3  = (const float*)d_in[7];
    const float* Wh1 = (const float*)d_in[8];
    const float* Bh1 = (const float*)d_in[9];
    const float* Wh2 = (const float*)d_in[10];
    const float* Bh2 = (const float*)d_in[11];
    float* out = (float*)d_out;
    const int n = out_size;                 // 32768 samples

    build_table_kernel<<<KNOTS + 1, 256, 0, stream>>>(Wh1, Bh1, Wh2, Bh2);

    const int nblocks = (n + 3) / 4;        // 4 waves/block, 1 sample/wave
    hyper_main<<<nblocks, 256, 0, stream>>>(coords, param, W1, B1, W2, B2,
                                            W3, B3, out, n);
}

// Round 2
// 47.284 us; speedup vs baseline: 2.1231x; 2.1231x over previous
//
#include <hip/hip_runtime.h>

#define HID 64
#define NROWS 1036
#define KNOTS 64    // intervals; table has KNOTS+1 rows
#define W2PAD 65    // padded LDS leading dim for W2^T
#define SPW 8       // samples per wave
#define ROWCHUNKS 4 // table-build row parallelism

// Static device-global table: g(p_j) for p_j = j/KNOTS, j = 0..KNOTS.
// Rebuilt every kernel_launch (deterministic), no d_ws dependence.
__device__ __align__(16) float gTable[(KNOTS + 1) * NROWS];

__global__ void build_table_kernel(const float* __restrict__ Wh1,
                                   const float* __restrict__ Bh1,
                                   const float* __restrict__ Wh2,
                                   const float* __restrict__ Bh2) {
    __shared__ float h[HID];
    const int j = blockIdx.x / ROWCHUNKS;          // 0..KNOTS
    const int chunk = blockIdx.x % ROWCHUNKS;
    const float p = (float)j / (float)KNOTS;
    const int t = threadIdx.x;
    if (t < HID) h[t] = tanhf(fmaf(p, Wh1[t], Bh1[t]));
    __syncthreads();
    const int r0 = chunk * ((NROWS + ROWCHUNKS - 1) / ROWCHUNKS);
    const int r1 = min(NROWS, r0 + ((NROWS + ROWCHUNKS - 1) / ROWCHUNKS));
    for (int i = r0 + t; i < r1; i += blockDim.x) {
        const float* row = Wh2 + i * HID;
        float acc = Bh2[i];
        #pragma unroll
        for (int k = 0; k < HID; ++k) acc = fmaf(row[k], h[k], acc);
        gTable[j * NROWS + i] = acc;
    }
}

__device__ inline float wave_sum(float v) {
    #pragma unroll
    for (int m = 32; m >= 1; m >>= 1) v += __shfl_xor(v, m, 64);
    return v;
}

__device__ inline float lerp1(float lo, float hi, float f) {
    return fmaf(f, hi - lo, lo);
}

__global__ __launch_bounds__(256) void hyper_main(
    const float* __restrict__ coords, const float* __restrict__ param,
    const float* __restrict__ W1, const float* __restrict__ B1,
    const float* __restrict__ W2, const float* __restrict__ B2,
    const float* __restrict__ W3, const float* __restrict__ B3,
    float* __restrict__ out, int n) {
    __shared__ float w2t[HID * W2PAD];  // W2^T padded: w2t[k*65 + h] = W2[h][k]
    __shared__ float x1s[4][HID];

    const int tid = threadIdx.x;

    // Stage W2 transposed into LDS (once per block). Padded stride 65:
    // write bank = (kk*65+hh)%32 = (kk+hh)%32 with kk per-lane -> 2-way (free).
    for (int idx = tid; idx < HID * HID; idx += 256) {
        const int hh = idx >> 6, kk = idx & 63;
        w2t[kk * W2PAD + hh] = W2[idx];
    }
    __syncthreads();

    const int wid = tid >> 6;           // wave id 0..3
    const int lane = tid & 63;          // = hidden index

    // Sample-invariant per-lane weights (hoisted out of the sample loop).
    const float w1a = W1[2 * lane];
    const float w1b = W1[2 * lane + 1];
    const float b1l = B1[lane];
    const float b2l = B2[lane];
    const float w3l = W3[lane];
    const float b3s = B3[0];

    const int base = blockIdx.x * (4 * SPW) + wid;

    for (int it = 0; it < SPW; ++it) {
        int s = base + it * 4;
        const bool valid = (s < n);
        if (s >= n) s = n - 1;

        const float c0 = coords[2 * s];
        const float c1 = coords[2 * s + 1];
        const float p = param[s];

        float pf = p * (float)KNOTS;
        int j = (int)pf;
        j = max(0, min(KNOTS - 1, j));
        const float f = pf - (float)j;

        const float* T0 = gTable + j * NROWS;
        const float* T1 = T0 + NROWS;

        // ---- per-lane low-rank fragments (lerped) ----
        float b1v[4], b2v[4], a2v[4], a3v[4], a1v[8], b3v[4];
        {
            const float4 lo = *(const float4*)(T0 + 8 + 4 * lane);
            const float4 hi = *(const float4*)(T1 + 8 + 4 * lane);
            b1v[0] = lerp1(lo.x, hi.x, f); b1v[1] = lerp1(lo.y, hi.y, f);
            b1v[2] = lerp1(lo.z, hi.z, f); b1v[3] = lerp1(lo.w, hi.w, f);
        }
        {
            const float4 lo = *(const float4*)(T0 + 520 + 4 * lane);
            const float4 hi = *(const float4*)(T1 + 520 + 4 * lane);
            b2v[0] = lerp1(lo.x, hi.x, f); b2v[1] = lerp1(lo.y, hi.y, f);
            b2v[2] = lerp1(lo.z, hi.z, f); b2v[3] = lerp1(lo.w, hi.w, f);
        }
        #pragma unroll
        for (int r = 0; r < 4; ++r) {
            a2v[r] = lerp1(T0[264 + 64 * r + lane], T1[264 + 64 * r + lane], f);
            a3v[r] = lerp1(T0[776 + 64 * r + lane], T1[776 + 64 * r + lane], f);
        }
        {   // shared across lanes: a1 rows 0..7, b3 rows 1032..1035
            const float4 lo0 = *(const float4*)(T0 + 0);
            const float4 hi0 = *(const float4*)(T1 + 0);
            const float4 lo1 = *(const float4*)(T0 + 4);
            const float4 hi1 = *(const float4*)(T1 + 4);
            a1v[0] = lerp1(lo0.x, hi0.x, f); a1v[1] = lerp1(lo0.y, hi0.y, f);
            a1v[2] = lerp1(lo0.z, hi0.z, f); a1v[3] = lerp1(lo0.w, hi0.w, f);
            a1v[4] = lerp1(lo1.x, hi1.x, f); a1v[5] = lerp1(lo1.y, hi1.y, f);
            a1v[6] = lerp1(lo1.z, hi1.z, f); a1v[7] = lerp1(lo1.w, hi1.w, f);
            const float4 lo2 = *(const float4*)(T0 + 1032);
            const float4 hi2 = *(const float4*)(T1 + 1032);
            b3v[0] = lerp1(lo2.x, hi2.x, f); b3v[1] = lerp1(lo2.y, hi2.y, f);
            b3v[2] = lerp1(lo2.z, hi2.z, f); b3v[3] = lerp1(lo2.w, hi2.w, f);
        }

        // ---- layer 1 ----
        float t1r[4];
        #pragma unroll
        for (int r = 0; r < 4; ++r)
            t1r[r] = fmaf(c0, a1v[2 * r], c1 * a1v[2 * r + 1]);
        float lr1 = t1r[0] * b1v[0] + t1r[1] * b1v[1] + t1r[2] * b1v[2] + t1r[3] * b1v[3];
        const float pre1 = fmaf(c0, w1a, fmaf(c1, w1b, lr1 + b1l));
        const float x1 = tanhf(pre1);

        x1s[wid][lane] = x1;   // same-wave write->read, no barrier needed

        // ---- W2 @ x1 (per-lane row dot; reads 2-way-free via pad) ----
        float ac0 = 0.f, ac1 = 0.f, ac2 = 0.f, ac3 = 0.f;
        #pragma unroll
        for (int k = 0; k < HID; k += 4) {
            ac0 = fmaf(w2t[(k + 0) * W2PAD + lane], x1s[wid][k + 0], ac0);
            ac1 = fmaf(w2t[(k + 1) * W2PAD + lane], x1s[wid][k + 1], ac1);
            ac2 = fmaf(w2t[(k + 2) * W2PAD + lane], x1s[wid][k + 2], ac2);
            ac3 = fmaf(w2t[(k + 3) * W2PAD + lane], x1s[wid][k + 3], ac3);
        }
        const float w2row = (ac0 + ac1) + (ac2 + ac3);

        // ---- low-rank 2: t2[r] = sum_k x1[k]*a2[r][k] (cross-lane) ----
        float t2r[4];
        #pragma unroll
        for (int r = 0; r < 4; ++r) t2r[r] = wave_sum(x1 * a2v[r]);
        const float lr2 = t2r[0] * b2v[0] + t2r[1] * b2v[1] + t2r[2] * b2v[2] + t2r[3] * b2v[3];
        const float x2 = tanhf(w2row + lr2 + b2l);

        // ---- output layer ----
        float o = wave_sum(w3l * x2);
        float t3r[4];
        #pragma unroll
        for (int r = 0; r < 4; ++r) t3r[r] = wave_sum(x2 * a3v[r]);

        if (lane == 0 && valid) {
            out[s] = o + t3r[0] * b3v[0] + t3r[1] * b3v[1] + t3r[2] * b3v[2]
                       + t3r[3] * b3v[3] + b3s;
        }
    }
}

extern "C" void kernel_launch(void* const* d_in, const int* in_sizes, int n_in,
                              void* d_out, int out_size, void* d_ws, size_t ws_size,
                              hipStream_t stream) {
    const float* coords = (const float*)d_in[0];
    const float* param  = (const float*)d_in[1];
    const float* W1  = (const float*)d_in[2];
    const float* B1  = (const float*)d_in[3];
    const float* W2  = (const float*)d_in[4];
    const float* B2  = (const float*)d_in[5];
    const float* W3  = (const float*)d_in[6];
    const float* B3  = (const float*)d_in[7];
    const float* Wh1 = (const float*)d_in[8];
    const float* Bh1 = (const float*)d_in[9];
    const float* Wh2 = (const float*)d_in[10];
    const float* Bh2 = (const float*)d_in[11];
    float* out = (float*)d_out;
    const int n = out_size;                 // 32768 samples

    build_table_kernel<<<(KNOTS + 1) * ROWCHUNKS, 256, 0, stream>>>(Wh1, Bh1, Wh2, Bh2);

    const int spb = 4 * SPW;                // samples per block
    const int nblocks = (n + spb - 1) / spb;
    hyper_main<<<nblocks, 256, 0, stream>>>(coords, param, W1, B1, W2, B2,
                                            W3, B3, out, n);
}

// Round 3
// 39.370 us; speedup vs baseline: 2.5499x; 1.2010x over previous
//
#include <hip/hip_runtime.h>

#define HID 64
#define NROWS 1036
#define KNOTS 64    // intervals; table has KNOTS+1 rows
#define SPW 8       // samples per wave
#define ROWCHUNKS 8 // table-build row parallelism

// Packed per-knot layout (1036 floats):
//   [0..7]      a1 (RANK x COORD, row-major)          -- uniform across lanes
//   [8..263]    b1[h][r] = 8 + 4h + r                 -- per-lane float4
//   [264..519]  a2t[k][r] = 264 + 4k + r (TRANSPOSED) -- per-lane float4
//   [520..775]  b2[h][r] = 520 + 4h + r               -- per-lane float4
//   [776..1031] a3t[k][r] = 776 + 4k + r (TRANSPOSED) -- per-lane float4
//   [1032..1035] b3[r]                                -- uniform
#define A1_OFF 0
#define B1_OFF 8
#define A2T_OFF 264
#define B2_OFF 520
#define A3T_OFF 776
#define B3_OFF 1032

__device__ __align__(16) float gTable[(KNOTS + 1) * NROWS];

__device__ inline int pack_idx(int i) {
    if (i >= A2T_OFF && i < B2_OFF) { int o = i - A2T_OFF; return A2T_OFF + ((o & 63) << 2) + (o >> 6); }
    if (i >= A3T_OFF && i < B3_OFF) { int o = i - A3T_OFF; return A3T_OFF + ((o & 63) << 2) + (o >> 6); }
    return i;
}

__global__ void build_table_kernel(const float* __restrict__ Wh1,
                                   const float* __restrict__ Bh1,
                                   const float* __restrict__ Wh2,
                                   const float* __restrict__ Bh2) {
    __shared__ float h[HID];
    const int j = blockIdx.x / ROWCHUNKS;          // 0..KNOTS
    const int chunk = blockIdx.x % ROWCHUNKS;
    const float p = (float)j / (float)KNOTS;
    const int t = threadIdx.x;
    if (t < HID) h[t] = tanhf(fmaf(p, Wh1[t], Bh1[t]));
    __syncthreads();
    const int rows = (NROWS + ROWCHUNKS - 1) / ROWCHUNKS;
    const int r0 = chunk * rows;
    const int r1 = min(NROWS, r0 + rows);
    for (int i = r0 + t; i < r1; i += blockDim.x) {
        const float4* row = (const float4*)(Wh2 + i * HID);
        float a0 = 0.f, a1 = 0.f, a2 = 0.f, a3 = 0.f;
        #pragma unroll
        for (int q = 0; q < 16; ++q) {
            float4 w = row[q];
            a0 = fmaf(w.x, h[4 * q + 0], a0);
            a1 = fmaf(w.y, h[4 * q + 1], a1);
            a2 = fmaf(w.z, h[4 * q + 2], a2);
            a3 = fmaf(w.w, h[4 * q + 3], a3);
        }
        gTable[j * NROWS + pack_idx(i)] = Bh2[i] + (a0 + a1) + (a2 + a3);
    }
}

// ---- DPP wave64 sum (VALU pipe only, no LDS). Result lands in lane 63. ----
template <int CTRL>
__device__ inline float dpp_add(float v) {
    int t = __builtin_amdgcn_update_dpp(0, __float_as_int(v), CTRL, 0xf, 0xf, true);
    return v + __int_as_float(t);
}
__device__ inline float wave_sum63(float v) {
    v = dpp_add<0x111>(v);  // row_shr:1
    v = dpp_add<0x112>(v);  // row_shr:2
    v = dpp_add<0x114>(v);  // row_shr:4
    v = dpp_add<0x118>(v);  // row_shr:8  -> lane15 of each row holds row sum
    v = dpp_add<0x142>(v);  // row_bcast15 -> lane31/63 accumulate pair sums
    v = dpp_add<0x143>(v);  // row_bcast31 -> lane63 holds full sum
    return v;
}
__device__ inline float bcast63(float v) {
    return __int_as_float(__builtin_amdgcn_readlane(__float_as_int(v), 63));
}

__device__ inline float tanh_fast(float x) {
    // branch-free: 1 - 2/(exp(2x)+1); |x| small here, v_exp/v_rcp precision ~1e-6
    return 1.0f - __fdividef(2.0f, __expf(2.0f * x) + 1.0f);
}

__device__ inline float4 ld4(const float* p) { return *(const float4*)p; }
__device__ inline float4 lerp4(float4 lo, float4 hi, float f) {
    float4 r;
    r.x = fmaf(f, hi.x - lo.x, lo.x);
    r.y = fmaf(f, hi.y - lo.y, lo.y);
    r.z = fmaf(f, hi.z - lo.z, lo.z);
    r.w = fmaf(f, hi.w - lo.w, lo.w);
    return r;
}

__global__ __launch_bounds__(256, 3) void hyper_main(
    const float* __restrict__ coords, const float* __restrict__ param,
    const float* __restrict__ W1, const float* __restrict__ B1,
    const float* __restrict__ W2, const float* __restrict__ B2,
    const float* __restrict__ W3, const float* __restrict__ B3,
    float* __restrict__ out, int n) {
    __shared__ __align__(16) float x1s[4][HID];   // only LDS left: x1 broadcast

    const int tid = threadIdx.x;
    const int wid = tid >> 6;
    const int lane = tid & 63;

    // W2 row for this lane -> registers, once per wave (amortized over SPW samples)
    float4 w2r[16];
    {
        const float4* wrow = (const float4*)(W2 + lane * HID);
        #pragma unroll
        for (int q = 0; q < 16; ++q) w2r[q] = wrow[q];
    }

    const float w1a = W1[2 * lane];
    const float w1b = W1[2 * lane + 1];
    const float b1l = B1[lane];
    const float b2l = B2[lane];
    const float w3l = W3[lane];
    const float b3s = B3[0];

    const int base = blockIdx.x * (4 * SPW) + wid;

    for (int it = 0; it < SPW; ++it) {
        int s = base + it * 4;
        const bool valid = (s < n);
        if (s >= n) s = n - 1;

        const float c0 = coords[2 * s];
        const float c1 = coords[2 * s + 1];
        const float p = param[s];

        float pf = p * (float)KNOTS;
        int j = (int)pf;
        j = max(0, min(KNOTS - 1, j));
        const float f = pf - (float)j;

        const float* T0 = gTable + j * NROWS;
        const float* T1 = T0 + NROWS;

        // per-lane packed fragments: one aligned float4 lerp each
        const float4 b1v = lerp4(ld4(T0 + B1_OFF  + 4 * lane), ld4(T1 + B1_OFF  + 4 * lane), f);
        const float4 a2v = lerp4(ld4(T0 + A2T_OFF + 4 * lane), ld4(T1 + A2T_OFF + 4 * lane), f);
        const float4 b2v = lerp4(ld4(T0 + B2_OFF  + 4 * lane), ld4(T1 + B2_OFF  + 4 * lane), f);
        const float4 a3v = lerp4(ld4(T0 + A3T_OFF + 4 * lane), ld4(T1 + A3T_OFF + 4 * lane), f);
        // lane-uniform pieces
        const float4 a1lo = lerp4(ld4(T0 + A1_OFF),     ld4(T1 + A1_OFF),     f);
        const float4 a1hi = lerp4(ld4(T0 + A1_OFF + 4), ld4(T1 + A1_OFF + 4), f);
        const float4 b3v  = lerp4(ld4(T0 + B3_OFF),     ld4(T1 + B3_OFF),     f);

        // ---- layer 1 (h = lane) ----
        const float t10 = fmaf(c0, a1lo.x, c1 * a1lo.y);
        const float t11 = fmaf(c0, a1lo.z, c1 * a1lo.w);
        const float t12 = fmaf(c0, a1hi.x, c1 * a1hi.y);
        const float t13 = fmaf(c0, a1hi.z, c1 * a1hi.w);
        const float lr1 = t10 * b1v.x + t11 * b1v.y + t12 * b1v.z + t13 * b1v.w;
        const float x1 = tanh_fast(fmaf(c0, w1a, fmaf(c1, w1b, lr1 + b1l)));

        x1s[wid][lane] = x1;   // same-wave write->read; no barrier needed

        // ---- W2 @ x1: registers x LDS-broadcast float4 ----
        const float4* xv = (const float4*)x1s[wid];
        float ac0 = 0.f, ac1 = 0.f, ac2 = 0.f, ac3 = 0.f;
        #pragma unroll
        for (int q = 0; q < 16; ++q) {
            const float4 xk = xv[q];
            ac0 = fmaf(w2r[q].x, xk.x, ac0);
            ac1 = fmaf(w2r[q].y, xk.y, ac1);
            ac2 = fmaf(w2r[q].z, xk.z, ac2);
            ac3 = fmaf(w2r[q].w, xk.w, ac3);
        }
        const float w2dot = (ac0 + ac1) + (ac2 + ac3);

        // ---- low-rank 2: four DPP reductions (VALU pipe) ----
        const float t20 = bcast63(wave_sum63(x1 * a2v.x));
        const float t21 = bcast63(wave_sum63(x1 * a2v.y));
        const float t22 = bcast63(wave_sum63(x1 * a2v.z));
        const float t23 = bcast63(wave_sum63(x1 * a2v.w));
        const float lr2 = t20 * b2v.x + t21 * b2v.y + t22 * b2v.z + t23 * b2v.w;
        const float x2 = tanh_fast(w2dot + lr2 + b2l);

        // ---- output layer folded into ONE reduction ----
        // out = sum_h x2[h]*(W3[h] + sum_r a3[h][r]*b3[r]) + B3
        const float weff = w3l + b3v.x * a3v.x + b3v.y * a3v.y
                               + b3v.z * a3v.z + b3v.w * a3v.w;
        const float osum = wave_sum63(x2 * weff);
        if (lane == 63 && valid) out[s] = osum + b3s;
    }
}

extern "C" void kernel_launch(void* const* d_in, const int* in_sizes, int n_in,
                              void* d_out, int out_size, void* d_ws, size_t ws_size,
                              hipStream_t stream) {
    const float* coords = (const float*)d_in[0];
    const float* param  = (const float*)d_in[1];
    const float* W1  = (const float*)d_in[2];
    const float* B1  = (const float*)d_in[3];
    const float* W2  = (const float*)d_in[4];
    const float* B2  = (const float*)d_in[5];
    const float* W3  = (const float*)d_in[6];
    const float* B3  = (const float*)d_in[7];
    const float* Wh1 = (const float*)d_in[8];
    const float* Bh1 = (const float*)d_in[9];
    const float* Wh2 = (const float*)d_in[10];
    const float* Bh2 = (const float*)d_in[11];
    float* out = (float*)d_out;
    const int n = out_size;                 // 32768 samples

    build_table_kernel<<<(KNOTS + 1) * ROWCHUNKS, 256, 0, stream>>>(Wh1, Bh1, Wh2, Bh2);

    const int spb = 4 * SPW;                // samples per block
    const int nblocks = (n + spb - 1) / spb;
    hyper_main<<<nblocks, 256, 0, stream>>>(coords, param, W1, B1, W2, B2,
                                            W3, B3, out, n);
}